// Round 14
// baseline (2404.938 us; speedup 1.0000x reference)
//
#include <hip/hip_runtime.h>

#define DINc 64
#define DHc  128
#define DEc  16
#define Gc   256
#define Rrep 64
#define SCB  1024
#define NT   64          // nodes per aggregation tile

typedef unsigned short u16;
typedef unsigned int   u32;
typedef __attribute__((ext_vector_type(8))) short bf8;
typedef __attribute__((ext_vector_type(4))) short bf4;
typedef __attribute__((ext_vector_type(4))) float f4;
typedef __attribute__((ext_vector_type(4))) unsigned int u32x4;
typedef _Float16 h2t __attribute__((ext_vector_type(2)));

__device__ __forceinline__ u16 f2b(float f) {
  u32 u = __builtin_bit_cast(u32, f);
  u32 r = u + 0x7FFFu + ((u >> 16) & 1u);   // round-to-nearest-even
  return (u16)(r >> 16);
}
__device__ __forceinline__ float b2f(u16 h) {
  u32 u = ((u32)h) << 16;
  return __builtin_bit_cast(float, u);
}
__device__ __forceinline__ float blo(u32 v) { return __builtin_bit_cast(float, v << 16); }
__device__ __forceinline__ float bhi(u32 v) { return __builtin_bit_cast(float, v & 0xFFFF0000u); }
__device__ __forceinline__ u32 pkbf(float a, float b) {
  return ((u32)f2b(b) << 16) | (u32)f2b(a);
}
__device__ __forceinline__ u32 pkh(float a, float b) {
  u16 ua = __builtin_bit_cast(u16, (_Float16)a);
  u16 ub = __builtin_bit_cast(u16, (_Float16)b);
  return ((u32)ub << 16) | ua;
}
__device__ __forceinline__ float fd2(u32 a, u32 b, float c) {
  return __builtin_amdgcn_fdot2(__builtin_bit_cast(h2t, a),
                                __builtin_bit_cast(h2t, b), c, false);
}

// ---- prep: weight prepack (0..27) + degree hist (28..539) + ea->f16 edge-order (540..) ----
__global__ __launch_bounds__(256) void k_prep(
    const float* __restrict__ w1a, const float* __restrict__ w1b,
    const float* __restrict__ w2a, const float* __restrict__ w2b,
    u16* __restrict__ wts,
    const int* __restrict__ dstA, const int nE, int* __restrict__ deg,
    const float* __restrict__ ea, u16* __restrict__ ea16e) {
  const int b = blockIdx.x;
  if (b < 28) {
    const int i = b * 256 + threadIdx.x;
    const float* src; int off;
    if      (i < 1024) { src = w1a; off = i; }
    else if (i < 3072) { src = w1b; off = i - 1024; }
    else if (i < 5120) { src = w2a; off = i - 3072; }
    else if (i < 7168) { src = w2b; off = i - 5120; }
    else return;
    float4 f0 = *(const float4*)(src + (size_t)off * 8);
    float4 f1 = *(const float4*)(src + (size_t)off * 8 + 4);
    bf8 v;
    v[0]=(short)f2b(f0.x); v[1]=(short)f2b(f0.y); v[2]=(short)f2b(f0.z); v[3]=(short)f2b(f0.w);
    v[4]=(short)f2b(f1.x); v[5]=(short)f2b(f1.y); v[6]=(short)f2b(f1.z); v[7]=(short)f2b(f1.w);
    *(bf8*)(wts + (size_t)i * 8) = v;
  } else if (b < 540) {
    for (int i = (b - 28) * 256 + threadIdx.x; i < nE; i += 512 * 256)
      atomicAdd(&deg[dstA[i]], 1);
  } else {
    const int nb = gridDim.x - 540;
    const int n8 = nE * 2;               // units of 8 floats (edge = 2 units)
    for (int i = (b - 540) * 256 + threadIdx.x; i < n8; i += nb * 256) {
      float4 f0 = *(const float4*)(ea + (size_t)i * 8);
      float4 f1 = *(const float4*)(ea + (size_t)i * 8 + 4);
      u32x4 w;
      w[0] = pkh(f0.x, f0.y); w[1] = pkh(f0.z, f0.w);
      w[2] = pkh(f1.x, f1.y); w[3] = pkh(f1.z, f1.w);
      *(u32x4*)(ea16e + (size_t)i * 8) = w;
    }
  }
}

// ---------------- CSR scan (rowptr used only at NT-tile granularity + hist) ----------------
__global__ __launch_bounds__(256) void k_scan_blk(const int* __restrict__ deg,
                                                  int* __restrict__ bsum, const int nN) {
  const int b = blockIdx.x, t = threadIdx.x;
  const int i0 = b * SCB + t * 4;
  int s = 0;
  #pragma unroll
  for (int q = 0; q < 4; ++q) { const int i = i0 + q; if (i < nN) s += deg[i]; }
  #pragma unroll
  for (int off = 32; off > 0; off >>= 1) s += __shfl_down(s, off);
  __shared__ int ws[4];
  if ((t & 63) == 0) ws[t >> 6] = s;
  __syncthreads();
  if (t == 0) bsum[b] = ws[0] + ws[1] + ws[2] + ws[3];
}

__global__ __launch_bounds__(256) void k_scan_fin(const int* __restrict__ deg,
                                                  const int* __restrict__ bsum,
                                                  int* __restrict__ rowptr,
                                                  const int nN, const int nB) {
  const int b = blockIdx.x, t = threadIdx.x;
  int p = 0;
  for (int i = t; i < b; i += 256) p += bsum[i];
  #pragma unroll
  for (int off = 32; off > 0; off >>= 1) p += __shfl_down(p, off);
  __shared__ int ws[4];
  __shared__ int sc[256];
  if ((t & 63) == 0) ws[t >> 6] = p;
  const int i0 = b * SCB + t * 4;
  int vals[4]; int s = 0;
  #pragma unroll
  for (int q = 0; q < 4; ++q) { const int i = i0 + q; vals[q] = (i < nN) ? deg[i] : 0; s += vals[q]; }
  sc[t] = s;
  __syncthreads();
  const int boff = ws[0] + ws[1] + ws[2] + ws[3];
  for (int off = 1; off < 256; off <<= 1) {
    int u = (t >= off) ? sc[t - off] : 0;
    __syncthreads();
    sc[t] += u;
    __syncthreads();
  }
  int run = boff + sc[t] - s;
  #pragma unroll
  for (int q = 0; q < 4; ++q) { const int i = i0 + q; if (i < nN) rowptr[i] = run; run += vals[q]; }
  if (b == nB - 1 && t == 255) rowptr[nN] = run;
}

// bucket-append: list[pos] = (eid<<6)|dst_local for the dst's NT-node tile (unsorted within tile)
__global__ __launch_bounds__(256) void k_bucket(const int* __restrict__ dstA, const int nE,
                                                const int* __restrict__ rowptr,
                                                int* __restrict__ cursorB,
                                                u32* __restrict__ list) {
  for (int i = blockIdx.x * 256 + threadIdx.x; i < nE; i += gridDim.x * 256) {
    const int d = dstA[i];
    const int bk = d >> 6;
    const int pos = rowptr[bk << 6] + atomicAdd(&cursorB[bk], 1);
    list[pos] = ((u32)i << 6) | (u32)(d & (NT - 1));
  }
}

// ---------------- gather via LDS fp32 atomic aggregation, one block per NT-node tile ----------------
template<int D, bool XF>
__global__ __launch_bounds__(256) void gather_lds(
    const float* __restrict__ xf, const u16* __restrict__ xb,
    const u32* __restrict__ list, const int* __restrict__ srcA,
    const u16* __restrict__ ea16e,
    const float* __restrict__ ewg, const float* __restrict__ ebg,
    const int* __restrict__ rowptr, u16* __restrict__ agg, const int nN)
{
  constexpr int PL = D / 64;
  __shared__ float ag[NT * D];           // 16KB (D=64) / 32KB (D=128)
  __shared__ u32 eas[4][64][8];          // 8KB
  const int tid = threadIdx.x;
  const int lane = tid & 63, wv = tid >> 6;
  u32 (*E)[8] = eas[wv];

  u32 wpk[8 * PL]; float ebr[PL];
  #pragma unroll
  for (int p = 0; p < PL; ++p) {
    const int d = lane * PL + p;
    ebr[p] = ebg[d];
    #pragma unroll
    for (int j = 0; j < 8; ++j)
      wpk[p * 8 + j] = pkh(ewg[d * 16 + 2 * j], ewg[d * 16 + 2 * j + 1]);
  }

  const int nb0 = blockIdx.x * NT;
  const int nb1 = min(nb0 + NT, nN);
  const int beg = rowptr[nb0], end = rowptr[nb1];

  for (int t = tid; t < NT * D; t += 256) ag[t] = 0.f;
  __syncthreads();

  for (int w = beg + wv * 64; w < end; w += 256) {
    const int cnt = min(64, end - w);
    u32 pk = 0; int sid = 0, dloc = 0;
    if (lane < cnt) {
      pk = list[w + lane];                       // sequential
      const int eid = (int)(pk >> 6);
      dloc = (int)(pk & (NT - 1));
      sid = srcA[eid];                           // random 4B (12.8MB, L3-hot)
      u32x4 a = *(const u32x4*)(ea16e + (size_t)eid * 16);      // random 32B row
      u32x4 b = *(const u32x4*)(ea16e + (size_t)eid * 16 + 8);
      *(u32x4*)&E[lane][0] = a;
      *(u32x4*)&E[lane][4] = b;
    }
    for (int i = 0; i < cnt; i += 8) {
      const int g = min(8, cnt - i);
      u32 xv[8]; float xs[8];
      #pragma unroll
      for (int q = 0; q < 8; ++q) {
        if (q < g) {
          const int s = __builtin_amdgcn_readlane(sid, i + q);
          if (XF) xs[q] = xf[(size_t)s * D + lane];
          else    xv[q] = *(const u32*)(xb + (size_t)s * D + lane * 2);
        }
      }
      #pragma unroll
      for (int q = 0; q < 8; ++q) {
        if (q < g) {
          const int e = i + q;
          const int dl = __builtin_amdgcn_readlane(dloc, e);
          u32x4 r0 = *(const u32x4*)&E[e][0];    // broadcast (same addr all lanes)
          u32x4 r1 = *(const u32x4*)&E[e][4];
          if (PL == 1) {
            float v = ebr[0];
            v = fd2(r0[0], wpk[0], v); v = fd2(r0[1], wpk[1], v);
            v = fd2(r0[2], wpk[2], v); v = fd2(r0[3], wpk[3], v);
            v = fd2(r1[0], wpk[4], v); v = fd2(r1[1], wpk[5], v);
            v = fd2(r1[2], wpk[6], v); v = fd2(r1[3], wpk[7], v);
            const float xval = XF ? xs[q] : blo(xv[q]);
            atomicAdd(&ag[dl * D + lane], fmaxf(xval + v, 0.f));
          } else {
            float v0 = ebr[0], v1 = ebr[1];
            v0 = fd2(r0[0], wpk[0], v0); v1 = fd2(r0[0], wpk[8],  v1);
            v0 = fd2(r0[1], wpk[1], v0); v1 = fd2(r0[1], wpk[9],  v1);
            v0 = fd2(r0[2], wpk[2], v0); v1 = fd2(r0[2], wpk[10], v1);
            v0 = fd2(r0[3], wpk[3], v0); v1 = fd2(r0[3], wpk[11], v1);
            v0 = fd2(r1[0], wpk[4], v0); v1 = fd2(r1[0], wpk[12], v1);
            v0 = fd2(r1[1], wpk[5], v0); v1 = fd2(r1[1], wpk[13], v1);
            v0 = fd2(r1[2], wpk[6], v0); v1 = fd2(r1[2], wpk[14], v1);
            v0 = fd2(r1[3], wpk[7], v0); v1 = fd2(r1[3], wpk[15], v1);
            atomicAdd(&ag[dl * D + lane * 2],     fmaxf(blo(xv[q]) + v0, 0.f));
            atomicAdd(&ag[dl * D + lane * 2 + 1], fmaxf(bhi(xv[q]) + v1, 0.f));
          }
        }
      }
    }
  }
  __syncthreads();
  // writeout: bf16 pairs, coalesced
  const int half = D / 2;
  for (int t = tid; t < NT * half; t += 256) {
    const int r = t / half, c = t % half;
    const int n = nb0 + r;
    if (n < nN)
      *(u32*)(agg + (size_t)n * D + c * 2) = pkbf(ag[r * D + c * 2], ag[r * D + c * 2 + 1]);
  }
}

// ---------------- MLP layer 1: t = relu((x+aggr) @ waT + ba) ----------------
template<int IN, bool XF>
__global__ __launch_bounds__(256) void k_l1(
    const float* __restrict__ xf, const u16* __restrict__ xbm,
    const u16* __restrict__ agb,
    const u16* __restrict__ waB, const float* __restrict__ ba,
    u16* __restrict__ tout, const int nN)
{
  __shared__ u16 wa_s[DHc * IN];
  __shared__ float ba_s[DHc];
  const int tid = threadIdx.x;
  constexpr int INC = IN / 8;
  for (int c = tid; c < DHc * INC; c += 256) {
    const int row = c / INC, kc = (c % INC) * 8;
    bf8 v = *(const bf8*)(waB + (size_t)row * IN + kc);
    *(bf8*)(wa_s + ((row * IN + kc) ^ ((row & 7) << 3))) = v;
  }
  if (tid < DHc) ba_s[tid] = ba[tid];
  __syncthreads();
  const int lane = tid & 63, wv = tid >> 6;
  const int lr = lane & 15, l4 = lane >> 4;
  const int nT = (nN + 15) >> 4;
  for (int tile = blockIdx.x * 4 + wv; tile < nT; tile += gridDim.x * 4) {
    const int node = tile * 16 + lr;
    const int n = min(node, nN - 1);
    bf8 bfr[IN / 32];
    #pragma unroll
    for (int ks = 0; ks < IN / 32; ++ks) {
      const int k0 = ks * 32 + l4 * 8;
      bf8 av = *(const bf8*)(agb + (size_t)n * IN + k0);
      bf8 v;
      if (XF) {
        float4 x0 = *(const float4*)(xf + (size_t)n * IN + k0);
        float4 x1 = *(const float4*)(xf + (size_t)n * IN + k0 + 4);
        v[0] = (short)f2b(x0.x + b2f((u16)av[0]));
        v[1] = (short)f2b(x0.y + b2f((u16)av[1]));
        v[2] = (short)f2b(x0.z + b2f((u16)av[2]));
        v[3] = (short)f2b(x0.w + b2f((u16)av[3]));
        v[4] = (short)f2b(x1.x + b2f((u16)av[4]));
        v[5] = (short)f2b(x1.y + b2f((u16)av[5]));
        v[6] = (short)f2b(x1.z + b2f((u16)av[6]));
        v[7] = (short)f2b(x1.w + b2f((u16)av[7]));
      } else {
        bf8 xv = *(const bf8*)(xbm + (size_t)n * IN + k0);
        #pragma unroll
        for (int j = 0; j < 8; ++j)
          v[j] = (short)f2b(b2f((u16)xv[j]) + b2f((u16)av[j]));
      }
      bfr[ks] = v;
    }
    const bool valid = node < nN;
    #pragma unroll
    for (int jt = 0; jt < 8; ++jt) {
      f4 c = {0.f, 0.f, 0.f, 0.f};
      #pragma unroll
      for (int ks = 0; ks < IN / 32; ++ks) {
        bf8 a = *(const bf8*)(wa_s + (((jt * 16 + lr) * IN + ks * 32 + l4 * 8) ^ ((lr & 7) << 3)));
        c = __builtin_amdgcn_mfma_f32_16x16x32_bf16(a, bfr[ks], c, 0, 0, 0);
      }
      if (valid) {
        float4 bav = *(const float4*)(ba_s + jt * 16 + l4 * 4);
        bf4 tv;
        tv[0] = (short)f2b(fmaxf(c[0] + bav.x, 0.f));
        tv[1] = (short)f2b(fmaxf(c[1] + bav.y, 0.f));
        tv[2] = (short)f2b(fmaxf(c[2] + bav.z, 0.f));
        tv[3] = (short)f2b(fmaxf(c[3] + bav.w, 0.f));
        *(bf4*)(tout + (size_t)node * DHc + jt * 16 + l4 * 4) = tv;
      }
    }
  }
}

// ---------------- MLP layer 2: out = relu(t @ wbT + bb) ----------------
template<bool FINAL>
__global__ __launch_bounds__(256) void k_l2(
    const u16* __restrict__ tin, const u16* __restrict__ wbB,
    const float* __restrict__ bb, u16* __restrict__ hout,
    const int* __restrict__ batch, float* __restrict__ sums, const int nN)
{
  __shared__ u16 wb_s[DHc * DHc];
  __shared__ float bb_s[DHc];
  const int tid = threadIdx.x;
  for (int c = tid; c < DHc * 16; c += 256) {
    const int row = c >> 4, kc = (c & 15) * 8;
    bf8 v = *(const bf8*)(wbB + (size_t)row * DHc + kc);
    *(bf8*)(wb_s + ((row * DHc + kc) ^ ((row & 7) << 3))) = v;
  }
  if (tid < DHc) bb_s[tid] = bb[tid];
  __syncthreads();
  const int lane = tid & 63, wv = tid >> 6;
  const int lr = lane & 15, l4 = lane >> 4;
  const int nT = (nN + 15) >> 4;
  const int gw0 = blockIdx.x * 4 + wv;
  const int rep = gw0 & (Rrep - 1);
  for (int tile = gw0; tile < nT; tile += gridDim.x * 4) {
    const int node0 = tile * 16;
    const int node = node0 + lr;
    const int n = min(node, nN - 1);
    bf8 tb[4];
    #pragma unroll
    for (int ks = 0; ks < 4; ++ks)
      tb[ks] = *(const bf8*)(tin + (size_t)n * DHc + ks * 32 + l4 * 8);
    const bool valid = node < nN;
    int gl = 0, g0 = 0; bool uni = false;
    if (FINAL) {
      gl = batch[n];
      g0 = __shfl(gl, 0);
      uni = __all(gl == g0) && (node0 + 16 <= nN);
    }
    #pragma unroll
    for (int jt = 0; jt < 8; ++jt) {
      f4 c = {0.f, 0.f, 0.f, 0.f};
      #pragma unroll
      for (int ks = 0; ks < 4; ++ks) {
        bf8 a = *(const bf8*)(wb_s + (((jt * 16 + lr) * DHc + ks * 32 + l4 * 8) ^ ((lr & 7) << 3)));
        c = __builtin_amdgcn_mfma_f32_16x16x32_bf16(a, tb[ks], c, 0, 0, 0);
      }
      float4 bbv = *(const float4*)(bb_s + jt * 16 + l4 * 4);
      float o0 = fmaxf(c[0] + bbv.x, 0.f);
      float o1 = fmaxf(c[1] + bbv.y, 0.f);
      float o2 = fmaxf(c[2] + bbv.z, 0.f);
      float o3 = fmaxf(c[3] + bbv.w, 0.f);
      if (!FINAL) {
        if (valid) {
          bf4 hv;
          hv[0] = (short)f2b(o0); hv[1] = (short)f2b(o1);
          hv[2] = (short)f2b(o2); hv[3] = (short)f2b(o3);
          *(bf4*)(hout + (size_t)node * DHc + jt * 16 + l4 * 4) = hv;
        }
      } else {
        if (uni) {
          #pragma unroll
          for (int off = 1; off < 16; off <<= 1) {
            o0 += __shfl_xor(o0, off);
            o1 += __shfl_xor(o1, off);
            o2 += __shfl_xor(o2, off);
            o3 += __shfl_xor(o3, off);
          }
          if (lr == 0) {
            float* dp = sums + ((size_t)rep * Gc + g0) * DHc + jt * 16 + l4 * 4;
            atomicAdd(dp + 0, o0); atomicAdd(dp + 1, o1);
            atomicAdd(dp + 2, o2); atomicAdd(dp + 3, o3);
          }
        } else if (valid) {
          float* dp = sums + ((size_t)rep * Gc + gl) * DHc + jt * 16 + l4 * 4;
          atomicAdd(dp + 0, o0); atomicAdd(dp + 1, o1);
          atomicAdd(dp + 2, o2); atomicAdd(dp + 3, o3);
        }
      }
    }
  }
}

// ---------------- final: reduce replicas, mean (binsearch counts), dot wf ----------------
__global__ __launch_bounds__(128) void pool_final(
    const float* __restrict__ sums, const int* __restrict__ batch,
    const float* __restrict__ wf, const float* __restrict__ bf,
    float* __restrict__ out, const int nN)
{
  const int g = blockIdx.x;
  const int j = threadIdx.x;
  float s = 0.f;
  for (int r = 0; r < Rrep; ++r) s += sums[((size_t)r * Gc + g) * DHc + j];
  int lo = 0, hi = nN;
  while (lo < hi) { int m = (lo + hi) >> 1; if (batch[m] < g) lo = m + 1; else hi = m; }
  int lo2 = lo, hi2 = nN;
  while (lo2 < hi2) { int m = (lo2 + hi2) >> 1; if (batch[m] < g + 1) lo2 = m + 1; else hi2 = m; }
  const float ct = fmaxf((float)(lo2 - lo), 1.f);
  __shared__ float red[128];
  red[j] = (s / ct) * wf[j];
  __syncthreads();
  for (int off = 64; off > 0; off >>= 1) { if (j < off) red[j] += red[j + off]; __syncthreads(); }
  if (j == 0) out[g] = red[0] + bf[0];
}

extern "C" void kernel_launch(void* const* d_in, const int* in_sizes, int n_in,
                              void* d_out, int out_size, void* d_ws, size_t ws_size,
                              hipStream_t stream) {
  const float* x    = (const float*)d_in[0];
  const int*   ei   = (const int*)d_in[1];
  const float* ea   = (const float*)d_in[2];
  const int*   batch= (const int*)d_in[3];
  const float* ew1  = (const float*)d_in[4];
  const float* eb1  = (const float*)d_in[5];
  const float* w1a  = (const float*)d_in[6];
  const float* b1a  = (const float*)d_in[7];
  const float* w1b  = (const float*)d_in[8];
  const float* b1b  = (const float*)d_in[9];
  const float* ew2  = (const float*)d_in[10];
  const float* eb2  = (const float*)d_in[11];
  const float* w2a  = (const float*)d_in[12];
  const float* b2a  = (const float*)d_in[13];
  const float* w2b  = (const float*)d_in[14];
  const float* b2b  = (const float*)d_in[15];
  const float* wf   = (const float*)d_in[16];
  const float* bf   = (const float*)d_in[17];
  float* out = (float*)d_out;

  const int nN = in_sizes[0] / DINc;
  const int nE = in_sizes[1] / 2;
  const int* srcA = ei;
  const int* dstA = ei + nE;
  const int nBk = (nN + NT - 1) / NT;

  char* wsb = (char*)d_ws;
  size_t o = 0;
  u16*   h1b    = (u16*)  (wsb + o); o += (size_t)nN * DHc * 2;
  u16*   tbuf   = (u16*)  (wsb + o); o += (size_t)nN * DHc * 2;
  u16*   agb    = (u16*)  (wsb + o); o += (size_t)nN * DHc * 2;
  float* sums   = (float*)(wsb + o); o += (size_t)Rrep * Gc * DHc * 4;
  int*   deg    = (int*)  (wsb + o); o += (size_t)nN * 4;
  int*   cursorB= (int*)  (wsb + o); o += (size_t)nBk * 4;
  int*   rowptr = (int*)  (wsb + o); o += (size_t)(nN + 1) * 4;
  int*   bsum   = (int*)  (wsb + o); o += (size_t)((nN + SCB - 1) / SCB) * 4; o = (o + 15) & ~(size_t)15;
  u32*   list   = (u32*)  (wsb + o); o += (size_t)nE * 4; o = (o + 15) & ~(size_t)15;
  u16*   ea16e  = (u16*)  (wsb + o); o += (size_t)nE * 16 * 2;
  u16*   wts    = (u16*)  (wsb + o); o += (size_t)57344 * 2;
  u16* w1ab = wts;
  u16* w1bb = wts + 8192;
  u16* w2ab = wts + 8192 + 16384;
  u16* w2bb = wts + 8192 + 32768;
  (void)ws_size; (void)n_in; (void)out_size;

  hipMemsetAsync(sums, 0, (size_t)Rrep * Gc * DHc * 4, stream);
  hipMemsetAsync(deg, 0, (size_t)(nN + nBk) * 4, stream);   // deg + cursorB adjacent

  const int nB = (nN + SCB - 1) / SCB;
  k_prep<<<28 + 512 + 256, 256, 0, stream>>>(w1a, w1b, w2a, w2b, wts,
                                             dstA, nE, deg, ea, ea16e);
  k_scan_blk<<<nB, 256, 0, stream>>>(deg, bsum, nN);
  k_scan_fin<<<nB, 256, 0, stream>>>(deg, bsum, rowptr, nN, nB);
  k_bucket<<<1024, 256, 0, stream>>>(dstA, nE, rowptr, cursorB, list);

  const int nT = (nN + 15) / 16;
  const int mg = (nT + 3) / 4;
  gather_lds<DINc, true><<<nBk, 256, 0, stream>>>(x, nullptr, list, srcA, ea16e,
                                                  ew1, eb1, rowptr, agb, nN);
  k_l1<DINc, true><<<mg, 256, 0, stream>>>(x, nullptr, agb, w1ab, b1a, tbuf, nN);
  k_l2<false><<<mg, 256, 0, stream>>>(tbuf, w1bb, b1b, h1b, nullptr, nullptr, nN);
  gather_lds<DHc, false><<<nBk, 256, 0, stream>>>(nullptr, h1b, list, srcA, ea16e,
                                                  ew2, eb2, rowptr, agb, nN);
  k_l1<DHc, false><<<mg, 256, 0, stream>>>(nullptr, h1b, agb, w2ab, b2a, tbuf, nN);
  k_l2<true><<<mg, 256, 0, stream>>>(tbuf, w2bb, b2b, nullptr, batch, sums, nN);
  pool_final<<<Gc, 128, 0, stream>>>(sums, batch, wf, bf, out, nN);
}

// Round 15
// 533.069 us; speedup vs baseline: 4.5115x; 4.5115x over previous
//
#include <hip/hip_runtime.h>

#define DINc 64
#define DHc  128
#define DEc  16
#define Gc   256
#define Rrep 64
#define SCB  1024

typedef unsigned short u16;
typedef unsigned int   u32;
typedef __attribute__((ext_vector_type(8))) short bf8;
typedef __attribute__((ext_vector_type(4))) short bf4;
typedef __attribute__((ext_vector_type(4))) float f4;
typedef __attribute__((ext_vector_type(4))) unsigned int u32x4;
typedef _Float16 h2t __attribute__((ext_vector_type(2)));

__device__ __forceinline__ u16 f2b(float f) {
  u32 u = __builtin_bit_cast(u32, f);
  u32 r = u + 0x7FFFu + ((u >> 16) & 1u);   // round-to-nearest-even
  return (u16)(r >> 16);
}
__device__ __forceinline__ float b2f(u16 h) {
  u32 u = ((u32)h) << 16;
  return __builtin_bit_cast(float, u);
}
__device__ __forceinline__ float blo(u32 v) { return __builtin_bit_cast(float, v << 16); }
__device__ __forceinline__ float bhi(u32 v) { return __builtin_bit_cast(float, v & 0xFFFF0000u); }
__device__ __forceinline__ u32 pkbf(float a, float b) {
  return ((u32)f2b(b) << 16) | (u32)f2b(a);
}
__device__ __forceinline__ u32 pkh(float a, float b) {
  u16 ua = __builtin_bit_cast(u16, (_Float16)a);
  u16 ub = __builtin_bit_cast(u16, (_Float16)b);
  return ((u32)ub << 16) | ua;
}
__device__ __forceinline__ float fd2(u32 a, u32 b, float c) {
  return __builtin_amdgcn_fdot2(__builtin_bit_cast(h2t, a),
                                __builtin_bit_cast(h2t, b), c, false);
}

// ---------------- prep: weight prepack (blocks 0..27) + degree hist (rest) ----------------
__global__ __launch_bounds__(256) void k_prep(
    const float* __restrict__ w1a, const float* __restrict__ w1b,
    const float* __restrict__ w2a, const float* __restrict__ w2b,
    u16* __restrict__ wts,
    const int* __restrict__ dstA, const int nE, int* __restrict__ deg) {
  const int b = blockIdx.x;
  if (b < 28) {
    const int i = b * 256 + threadIdx.x;
    const float* src; int off;
    if      (i < 1024) { src = w1a; off = i; }
    else if (i < 3072) { src = w1b; off = i - 1024; }
    else if (i < 5120) { src = w2a; off = i - 3072; }
    else if (i < 7168) { src = w2b; off = i - 5120; }
    else return;
    float4 f0 = *(const float4*)(src + (size_t)off * 8);
    float4 f1 = *(const float4*)(src + (size_t)off * 8 + 4);
    bf8 v;
    v[0]=(short)f2b(f0.x); v[1]=(short)f2b(f0.y); v[2]=(short)f2b(f0.z); v[3]=(short)f2b(f0.w);
    v[4]=(short)f2b(f1.x); v[5]=(short)f2b(f1.y); v[6]=(short)f2b(f1.z); v[7]=(short)f2b(f1.w);
    *(bf8*)(wts + (size_t)i * 8) = v;
  } else {
    const int nb = gridDim.x - 28;
    for (int i = (b - 28) * 256 + threadIdx.x; i < nE; i += nb * 256)
      atomicAdd(&deg[dstA[i]], 1);
  }
}

// ---------------- CSR scan ----------------
__global__ __launch_bounds__(256) void k_scan_blk(const int* __restrict__ deg,
                                                  int* __restrict__ bsum, const int nN) {
  const int b = blockIdx.x, t = threadIdx.x;
  const int i0 = b * SCB + t * 4;
  int s = 0;
  #pragma unroll
  for (int q = 0; q < 4; ++q) { const int i = i0 + q; if (i < nN) s += deg[i]; }
  #pragma unroll
  for (int off = 32; off > 0; off >>= 1) s += __shfl_down(s, off);
  __shared__ int ws[4];
  if ((t & 63) == 0) ws[t >> 6] = s;
  __syncthreads();
  if (t == 0) bsum[b] = ws[0] + ws[1] + ws[2] + ws[3];
}

__global__ __launch_bounds__(256) void k_scan_fin(const int* __restrict__ deg,
                                                  const int* __restrict__ bsum,
                                                  int* __restrict__ rowptr,
                                                  const int nN, const int nB) {
  const int b = blockIdx.x, t = threadIdx.x;
  int p = 0;
  for (int i = t; i < b; i += 256) p += bsum[i];
  #pragma unroll
  for (int off = 32; off > 0; off >>= 1) p += __shfl_down(p, off);
  __shared__ int ws[4];
  __shared__ int sc[256];
  if ((t & 63) == 0) ws[t >> 6] = p;
  const int i0 = b * SCB + t * 4;
  int vals[4]; int s = 0;
  #pragma unroll
  for (int q = 0; q < 4; ++q) { const int i = i0 + q; vals[q] = (i < nN) ? deg[i] : 0; s += vals[q]; }
  sc[t] = s;
  __syncthreads();
  const int boff = ws[0] + ws[1] + ws[2] + ws[3];
  for (int off = 1; off < 256; off <<= 1) {
    int u = (t >= off) ? sc[t - off] : 0;
    __syncthreads();
    sc[t] += u;
    __syncthreads();
  }
  int run = boff + sc[t] - s;
  #pragma unroll
  for (int q = 0; q < 4; ++q) { const int i = i0 + q; if (i < nN) rowptr[i] = run; run += vals[q]; }
  if (b == nB - 1 && t == 255) rowptr[nN] = run;
}

// fill: ONE 64B record per edge {src, dst, ea_f16[16], pad} — full-line write, no RFO
__global__ __launch_bounds__(256) void k_fill(const int* __restrict__ dstA,
                                              const int* __restrict__ srcA,
                                              const float* __restrict__ ea, const int nE,
                                              const int* __restrict__ rowptr,
                                              int* __restrict__ cursor,
                                              u32* __restrict__ rec) {
  for (int i = blockIdx.x * 256 + threadIdx.x; i < nE; i += gridDim.x * 256) {
    const int d = dstA[i];
    const int pos = rowptr[d] + atomicAdd(&cursor[d], 1);
    const float4* ep = (const float4*)(ea + (size_t)i * 16);
    float4 a0 = ep[0], a1 = ep[1], a2 = ep[2], a3 = ep[3];
    u32x4 w0, w1, w2, w3;
    w0[0] = (u32)srcA[i]; w0[1] = (u32)d;
    w0[2] = pkh(a0.x, a0.y); w0[3] = pkh(a0.z, a0.w);
    w1[0] = pkh(a1.x, a1.y); w1[1] = pkh(a1.z, a1.w);
    w1[2] = pkh(a2.x, a2.y); w1[3] = pkh(a2.z, a2.w);
    w2[0] = pkh(a3.x, a3.y); w2[1] = pkh(a3.z, a3.w);
    w2[2] = 0u; w2[3] = 0u;
    w3[0] = 0u; w3[1] = 0u; w3[2] = 0u; w3[3] = 0u;
    u32* rp = rec + (size_t)pos * 16;
    *(u32x4*)(rp + 0)  = w0;
    *(u32x4*)(rp + 4)  = w1;
    *(u32x4*)(rp + 8)  = w2;
    *(u32x4*)(rp + 12) = w3;
  }
}

__device__ __forceinline__ int span_lb(const int* __restrict__ rp, int nN, int target) {
  int lo = 0, hi = nN;
  while (lo < hi) { int m = (lo + hi) >> 1; if (rp[m] < target) lo = m + 1; else hi = m; }
  return lo;
}

// ---------------- gather v4: flat loop + cnt==64 & group-skip fast paths ----------------
#define STORE_N(NODE) do { \
  if (PL == 2) *(u32*)(agg + (size_t)(NODE) * 128 + lane * 2) = pkbf(acc0, acc1); \
  else         agg[(size_t)(NODE) * 64 + lane] = f2b(acc0); \
} while (0)
#define STORE_Z(NODE) do { \
  if (PL == 2) *(u32*)(agg + (size_t)(NODE) * 128 + lane * 2) = 0u; \
  else         agg[(size_t)(NODE) * 64 + lane] = 0; \
} while (0)
#define BCHK(EIDX) do { \
  if ((bmask >> (EIDX)) & 1ull) { \
    const int nd = __builtin_amdgcn_readlane(dl, (EIDX)); \
    if (cur >= n0) STORE_N(cur); \
    for (int m = cur + 1; m < nd; ++m) STORE_Z(m); \
    acc0 = 0.f; acc1 = 0.f; cur = nd; \
  } \
} while (0)
#define ACC_EDGE(EIDX, Q) do { \
  u32x4 r0 = *(const u32x4*)&E[(EIDX)][0]; \
  u32x4 r1 = *(const u32x4*)&E[(EIDX)][4]; \
  if (PL == 1) { \
    float v = ebr[0]; \
    v = fd2(r0[0], wpk[0], v); v = fd2(r0[1], wpk[1], v); \
    v = fd2(r0[2], wpk[2], v); v = fd2(r0[3], wpk[3], v); \
    v = fd2(r1[0], wpk[4], v); v = fd2(r1[1], wpk[5], v); \
    v = fd2(r1[2], wpk[6], v); v = fd2(r1[3], wpk[7], v); \
    const float xval = XF ? xs[Q] : blo(xv[Q]); \
    acc0 += fmaxf(xval + v, 0.f); \
  } else { \
    float v0 = ebr[0], v1 = ebr[1]; \
    v0 = fd2(r0[0], wpk[0], v0); v1 = fd2(r0[0], wpk[8],  v1); \
    v0 = fd2(r0[1], wpk[1], v0); v1 = fd2(r0[1], wpk[9],  v1); \
    v0 = fd2(r0[2], wpk[2], v0); v1 = fd2(r0[2], wpk[10], v1); \
    v0 = fd2(r0[3], wpk[3], v0); v1 = fd2(r0[3], wpk[11], v1); \
    v0 = fd2(r1[0], wpk[4], v0); v1 = fd2(r1[0], wpk[12], v1); \
    v0 = fd2(r1[1], wpk[5], v0); v1 = fd2(r1[1], wpk[13], v1); \
    v0 = fd2(r1[2], wpk[6], v0); v1 = fd2(r1[2], wpk[14], v1); \
    v0 = fd2(r1[3], wpk[7], v0); v1 = fd2(r1[3], wpk[15], v1); \
    acc0 += fmaxf(blo(xv[Q]) + v0, 0.f); \
    acc1 += fmaxf(bhi(xv[Q]) + v1, 0.f); \
  } \
} while (0)

template<int D, bool XF>
__global__ __launch_bounds__(256) void gather4(
    const float* __restrict__ xf, const u16* __restrict__ xb,
    const u32* __restrict__ rec,
    const float* __restrict__ ewg, const float* __restrict__ ebg,
    const int* __restrict__ rowptr, u16* __restrict__ agg,
    const int nN, const int nE)
{
  constexpr int PL = D / 64;
  __shared__ u32 eas[4][64][8];          // 8KB, wave-private slices
  const int lane = threadIdx.x & 63, wv = threadIdx.x >> 6;
  u32 (*E)[8] = eas[wv];

  u32 wpk[8 * PL]; float ebr[PL];
  #pragma unroll
  for (int p = 0; p < PL; ++p) {
    const int d = lane * PL + p;
    ebr[p] = ebg[d];
    #pragma unroll
    for (int j = 0; j < 8; ++j)
      wpk[p * 8 + j] = pkh(ewg[d * 16 + 2 * j], ewg[d * 16 + 2 * j + 1]);
  }

  const int wgid = blockIdx.x * 4 + wv;
  const int nw   = gridDim.x * 4;
  const int t0 = (int)((long long)nE * wgid / nw);
  const int t1 = (int)((long long)nE * (wgid + 1) / nw);
  const int n0 = span_lb(rowptr, nN, t0);
  const int n1 = (wgid == nw - 1) ? nN : span_lb(rowptr, nN, t1);
  if (n0 >= n1) return;
  const int e0 = rowptr[n0], e1 = rowptr[n1];

  float acc0 = 0.f, acc1 = 0.f;
  int cur = n0 - 1;

  for (int chunk = e0; chunk < e1; chunk += 64) {
    const int cnt = min(64, e1 - chunk);
    int sid = 0, dl = -1;
    if (lane < cnt) {                    // one 64B record per lane, single line
      const u32* rp = rec + (size_t)(chunk + lane) * 16;
      u32x4 r0 = *(const u32x4*)(rp + 0);
      u32x4 r1 = *(const u32x4*)(rp + 4);
      u32x4 r2 = *(const u32x4*)(rp + 8);
      sid = (int)r0[0];
      dl  = (int)r0[1];
      E[lane][0] = r0[2]; E[lane][1] = r0[3];
      E[lane][2] = r1[0]; E[lane][3] = r1[1];
      E[lane][4] = r1[2]; E[lane][5] = r1[3];
      E[lane][6] = r2[0]; E[lane][7] = r2[1];
    }
    const int pd = __shfl_up(dl, 1);
    const bool bnd = (lane < cnt) && (dl != ((lane == 0) ? cur : pd));
    const unsigned long long bmask = __ballot(bnd);

    if (cnt == 64) {
      #pragma unroll 1
      for (int i = 0; i < 64; i += 8) {
        u32 xv[8]; float xs[8];
        #pragma unroll
        for (int q = 0; q < 8; ++q) {
          const int s = __builtin_amdgcn_readlane(sid, i + q);
          if (XF) xs[q] = xf[(size_t)s * D + lane];
          else    xv[q] = *(const u32*)(xb + (size_t)s * D + lane * 2);
        }
        const u32 gm = (u32)(bmask >> i) & 0xFFu;
        if (gm == 0) {                    // no node boundary in this group
          #pragma unroll
          for (int q = 0; q < 8; ++q) ACC_EDGE(i + q, q);
        } else {
          #pragma unroll
          for (int q = 0; q < 8; ++q) { BCHK(i + q); ACC_EDGE(i + q, q); }
        }
      }
    } else {
      for (int i = 0; i < cnt; i += 8) {
        const int g = min(8, cnt - i);
        u32 xv[8]; float xs[8];
        #pragma unroll
        for (int q = 0; q < 8; ++q) {
          if (q < g) {
            const int s = __builtin_amdgcn_readlane(sid, i + q);
            if (XF) xs[q] = xf[(size_t)s * D + lane];
            else    xv[q] = *(const u32*)(xb + (size_t)s * D + lane * 2);
          }
        }
        #pragma unroll
        for (int q = 0; q < 8; ++q) {
          if (q < g) { BCHK(i + q); ACC_EDGE(i + q, q); }
        }
      }
    }
  }
  if (cur >= n0) STORE_N(cur);
  for (int m = cur + 1; m < n1; ++m) STORE_Z(m);
}

// ---------------- MLP layer 1: t = relu((x+aggr) @ waT + ba) ----------------
template<int IN, bool XF>
__global__ __launch_bounds__(256) void k_l1(
    const float* __restrict__ xf, const u16* __restrict__ xbm,
    const u16* __restrict__ agb,
    const u16* __restrict__ waB, const float* __restrict__ ba,
    u16* __restrict__ tout, const int nN)
{
  __shared__ u16 wa_s[DHc * IN];
  __shared__ float ba_s[DHc];
  const int tid = threadIdx.x;
  constexpr int INC = IN / 8;
  for (int c = tid; c < DHc * INC; c += 256) {
    const int row = c / INC, kc = (c % INC) * 8;
    bf8 v = *(const bf8*)(waB + (size_t)row * IN + kc);
    *(bf8*)(wa_s + ((row * IN + kc) ^ ((row & 7) << 3))) = v;
  }
  if (tid < DHc) ba_s[tid] = ba[tid];
  __syncthreads();
  const int lane = tid & 63, wv = tid >> 6;
  const int lr = lane & 15, l4 = lane >> 4;
  const int nT = (nN + 15) >> 4;
  for (int tile = blockIdx.x * 4 + wv; tile < nT; tile += gridDim.x * 4) {
    const int node = tile * 16 + lr;
    const int n = min(node, nN - 1);
    bf8 bfr[IN / 32];
    #pragma unroll
    for (int ks = 0; ks < IN / 32; ++ks) {
      const int k0 = ks * 32 + l4 * 8;
      bf8 av = *(const bf8*)(agb + (size_t)n * IN + k0);
      bf8 v;
      if (XF) {
        float4 x0 = *(const float4*)(xf + (size_t)n * IN + k0);
        float4 x1 = *(const float4*)(xf + (size_t)n * IN + k0 + 4);
        v[0] = (short)f2b(x0.x + b2f((u16)av[0]));
        v[1] = (short)f2b(x0.y + b2f((u16)av[1]));
        v[2] = (short)f2b(x0.z + b2f((u16)av[2]));
        v[3] = (short)f2b(x0.w + b2f((u16)av[3]));
        v[4] = (short)f2b(x1.x + b2f((u16)av[4]));
        v[5] = (short)f2b(x1.y + b2f((u16)av[5]));
        v[6] = (short)f2b(x1.z + b2f((u16)av[6]));
        v[7] = (short)f2b(x1.w + b2f((u16)av[7]));
      } else {
        bf8 xv = *(const bf8*)(xbm + (size_t)n * IN + k0);
        #pragma unroll
        for (int j = 0; j < 8; ++j)
          v[j] = (short)f2b(b2f((u16)xv[j]) + b2f((u16)av[j]));
      }
      bfr[ks] = v;
    }
    const bool valid = node < nN;
    #pragma unroll
    for (int jt = 0; jt < 8; ++jt) {
      f4 c = {0.f, 0.f, 0.f, 0.f};
      #pragma unroll
      for (int ks = 0; ks < IN / 32; ++ks) {
        bf8 a = *(const bf8*)(wa_s + (((jt * 16 + lr) * IN + ks * 32 + l4 * 8) ^ ((lr & 7) << 3)));
        c = __builtin_amdgcn_mfma_f32_16x16x32_bf16(a, bfr[ks], c, 0, 0, 0);
      }
      if (valid) {
        float4 bav = *(const float4*)(ba_s + jt * 16 + l4 * 4);
        bf4 tv;
        tv[0] = (short)f2b(fmaxf(c[0] + bav.x, 0.f));
        tv[1] = (short)f2b(fmaxf(c[1] + bav.y, 0.f));
        tv[2] = (short)f2b(fmaxf(c[2] + bav.z, 0.f));
        tv[3] = (short)f2b(fmaxf(c[3] + bav.w, 0.f));
        *(bf4*)(tout + (size_t)node * DHc + jt * 16 + l4 * 4) = tv;
      }
    }
  }
}

// ---------------- MLP layer 2: out = relu(t @ wbT + bb) ----------------
template<bool FINAL>
__global__ __launch_bounds__(256) void k_l2(
    const u16* __restrict__ tin, const u16* __restrict__ wbB,
    const float* __restrict__ bb, u16* __restrict__ hout,
    const int* __restrict__ batch, float* __restrict__ sums, const int nN)
{
  __shared__ u16 wb_s[DHc * DHc];
  __shared__ float bb_s[DHc];
  const int tid = threadIdx.x;
  for (int c = tid; c < DHc * 16; c += 256) {
    const int row = c >> 4, kc = (c & 15) * 8;
    bf8 v = *(const bf8*)(wbB + (size_t)row * DHc + kc);
    *(bf8*)(wb_s + ((row * DHc + kc) ^ ((row & 7) << 3))) = v;
  }
  if (tid < DHc) bb_s[tid] = bb[tid];
  __syncthreads();
  const int lane = tid & 63, wv = tid >> 6;
  const int lr = lane & 15, l4 = lane >> 4;
  const int nT = (nN + 15) >> 4;
  const int gw0 = blockIdx.x * 4 + wv;
  const int rep = gw0 & (Rrep - 1);
  for (int tile = gw0; tile < nT; tile += gridDim.x * 4) {
    const int node0 = tile * 16;
    const int node = node0 + lr;
    const int n = min(node, nN - 1);
    bf8 tb[4];
    #pragma unroll
    for (int ks = 0; ks < 4; ++ks)
      tb[ks] = *(const bf8*)(tin + (size_t)n * DHc + ks * 32 + l4 * 8);
    const bool valid = node < nN;
    int gl = 0, g0 = 0; bool uni = false;
    if (FINAL) {
      gl = batch[n];
      g0 = __shfl(gl, 0);
      uni = __all(gl == g0) && (node0 + 16 <= nN);
    }
    #pragma unroll
    for (int jt = 0; jt < 8; ++jt) {
      f4 c = {0.f, 0.f, 0.f, 0.f};
      #pragma unroll
      for (int ks = 0; ks < 4; ++ks) {
        bf8 a = *(const bf8*)(wb_s + (((jt * 16 + lr) * DHc + ks * 32 + l4 * 8) ^ ((lr & 7) << 3)));
        c = __builtin_amdgcn_mfma_f32_16x16x32_bf16(a, tb[ks], c, 0, 0, 0);
      }
      float4 bbv = *(const float4*)(bb_s + jt * 16 + l4 * 4);
      float o0 = fmaxf(c[0] + bbv.x, 0.f);
      float o1 = fmaxf(c[1] + bbv.y, 0.f);
      float o2 = fmaxf(c[2] + bbv.z, 0.f);
      float o3 = fmaxf(c[3] + bbv.w, 0.f);
      if (!FINAL) {
        if (valid) {
          bf4 hv;
          hv[0] = (short)f2b(o0); hv[1] = (short)f2b(o1);
          hv[2] = (short)f2b(o2); hv[3] = (short)f2b(o3);
          *(bf4*)(hout + (size_t)node * DHc + jt * 16 + l4 * 4) = hv;
        }
      } else {
        if (uni) {
          #pragma unroll
          for (int off = 1; off < 16; off <<= 1) {
            o0 += __shfl_xor(o0, off);
            o1 += __shfl_xor(o1, off);
            o2 += __shfl_xor(o2, off);
            o3 += __shfl_xor(o3, off);
          }
          if (lr == 0) {
            float* dp = sums + ((size_t)rep * Gc + g0) * DHc + jt * 16 + l4 * 4;
            atomicAdd(dp + 0, o0); atomicAdd(dp + 1, o1);
            atomicAdd(dp + 2, o2); atomicAdd(dp + 3, o3);
          }
        } else if (valid) {
          float* dp = sums + ((size_t)rep * Gc + gl) * DHc + jt * 16 + l4 * 4;
          atomicAdd(dp + 0, o0); atomicAdd(dp + 1, o1);
          atomicAdd(dp + 2, o2); atomicAdd(dp + 3, o3);
        }
      }
    }
  }
}

// ---------------- final: reduce replicas, mean (binsearch counts), dot wf ----------------
__global__ __launch_bounds__(128) void pool_final(
    const float* __restrict__ sums, const int* __restrict__ batch,
    const float* __restrict__ wf, const float* __restrict__ bf,
    float* __restrict__ out, const int nN)
{
  const int g = blockIdx.x;
  const int j = threadIdx.x;
  float s = 0.f;
  for (int r = 0; r < Rrep; ++r) s += sums[((size_t)r * Gc + g) * DHc + j];
  int lo = 0, hi = nN;
  while (lo < hi) { int m = (lo + hi) >> 1; if (batch[m] < g) lo = m + 1; else hi = m; }
  int lo2 = lo, hi2 = nN;
  while (lo2 < hi2) { int m = (lo2 + hi2) >> 1; if (batch[m] < g + 1) lo2 = m + 1; else hi2 = m; }
  const float ct = fmaxf((float)(lo2 - lo), 1.f);
  __shared__ float red[128];
  red[j] = (s / ct) * wf[j];
  __syncthreads();
  for (int off = 64; off > 0; off >>= 1) { if (j < off) red[j] += red[j + off]; __syncthreads(); }
  if (j == 0) out[g] = red[0] + bf[0];
}

extern "C" void kernel_launch(void* const* d_in, const int* in_sizes, int n_in,
                              void* d_out, int out_size, void* d_ws, size_t ws_size,
                              hipStream_t stream) {
  const float* x    = (const float*)d_in[0];
  const int*   ei   = (const int*)d_in[1];
  const float* ea   = (const float*)d_in[2];
  const int*   batch= (const int*)d_in[3];
  const float* ew1  = (const float*)d_in[4];
  const float* eb1  = (const float*)d_in[5];
  const float* w1a  = (const float*)d_in[6];
  const float* b1a  = (const float*)d_in[7];
  const float* w1b  = (const float*)d_in[8];
  const float* b1b  = (const float*)d_in[9];
  const float* ew2  = (const float*)d_in[10];
  const float* eb2  = (const float*)d_in[11];
  const float* w2a  = (const float*)d_in[12];
  const float* b2a  = (const float*)d_in[13];
  const float* w2b  = (const float*)d_in[14];
  const float* b2b  = (const float*)d_in[15];
  const float* wf   = (const float*)d_in[16];
  const float* bf   = (const float*)d_in[17];
  float* out = (float*)d_out;

  const int nN = in_sizes[0] / DINc;
  const int nE = in_sizes[1] / 2;
  const int* srcA = ei;
  const int* dstA = ei + nE;

  char* wsb = (char*)d_ws;
  size_t o = 0;
  u16*   h1b    = (u16*)  (wsb + o); o += (size_t)nN * DHc * 2;
  u16*   tbuf   = (u16*)  (wsb + o); o += (size_t)nN * DHc * 2;
  u16*   agb    = (u16*)  (wsb + o); o += (size_t)nN * DHc * 2;
  float* sums   = (float*)(wsb + o); o += (size_t)Rrep * Gc * DHc * 4;
  int*   deg    = (int*)  (wsb + o); o += (size_t)nN * 4;
  int*   cursor = (int*)  (wsb + o); o += (size_t)nN * 4;
  int*   rowptr = (int*)  (wsb + o); o += (size_t)(nN + 1) * 4;
  int*   bsum   = (int*)  (wsb + o); o += (size_t)((nN + SCB - 1) / SCB) * 4; o = (o + 63) & ~(size_t)63;
  u32*   rec    = (u32*)  (wsb + o); o += (size_t)nE * 64;
  u16*   wts    = (u16*)  (wsb + o); o += (size_t)57344 * 2;
  u16* w1ab = wts;
  u16* w1bb = wts + 8192;
  u16* w2ab = wts + 8192 + 16384;
  u16* w2bb = wts + 8192 + 32768;
  (void)ws_size; (void)n_in; (void)out_size;

  hipMemsetAsync(sums, 0, (size_t)Rrep * Gc * DHc * 4, stream);
  hipMemsetAsync(deg, 0, (size_t)nN * 8, stream);

  const int nB = (nN + SCB - 1) / SCB;
  k_prep<<<28 + 512, 256, 0, stream>>>(w1a, w1b, w2a, w2b, wts, dstA, nE, deg);
  k_scan_blk<<<nB, 256, 0, stream>>>(deg, bsum, nN);
  k_scan_fin<<<nB, 256, 0, stream>>>(deg, bsum, rowptr, nN, nB);
  k_fill<<<1024, 256, 0, stream>>>(dstA, srcA, ea, nE, rowptr, cursor, rec);

  const int nT = (nN + 15) / 16;
  const int mg = (nT + 3) / 4;
  gather4<DINc, true><<<2048, 256, 0, stream>>>(x, nullptr, rec,
                                                ew1, eb1, rowptr, agb, nN, nE);
  k_l1<DINc, true><<<mg, 256, 0, stream>>>(x, nullptr, agb, w1ab, b1a, tbuf, nN);
  k_l2<false><<<mg, 256, 0, stream>>>(tbuf, w1bb, b1b, h1b, nullptr, nullptr, nN);
  gather4<DHc, false><<<2048, 256, 0, stream>>>(nullptr, h1b, rec,
                                                ew2, eb2, rowptr, agb, nN, nE);
  k_l1<DHc, false><<<mg, 256, 0, stream>>>(nullptr, h1b, agb, w2ab, b2a, tbuf, nN);
  k_l2<true><<<mg, 256, 0, stream>>>(tbuf, w2bb, b2b, nullptr, batch, sums, nN);
  pool_final<<<Gc, 128, 0, stream>>>(sums, batch, wf, bf, out, nN);
}